// Round 2
// baseline (614.714 us; speedup 1.0000x reference)
//
#include <hip/hip_runtime.h>
#include <hip/hip_bf16.h>
#include <math.h>

#define N_NODES 50000
#define K_NBR   16
#define DIM     256
#define O_DIM   256
#define H_HEADS 8
#define HD      32
#define EPS     1e-5f
// SCALE = sqrt(HD) = sqrt(32)
#define INV_SCALE 0.17677669529663687f  // 1/sqrt(32)

__device__ __forceinline__ float sigmoidf_(float x) {
    return 1.0f / (1.0f + __expf(-x));
}

// ---------------------------------------------------------------------------
// Kernel 1: Q = h@Wq + bq ; Kall = h@Wk + bk   (fused, reads h once)
// 32 rows per block, 256 threads (thread = output column).
// ---------------------------------------------------------------------------
__global__ __launch_bounds__(256) void qk_proj_kernel(
    const float* __restrict__ h,
    const float* __restrict__ Wq, const float* __restrict__ bq,
    const float* __restrict__ Wk, const float* __restrict__ bk,
    float* __restrict__ Q, float* __restrict__ Kall)
{
    __shared__ float hs[32][DIM];
    const int row0 = blockIdx.x * 32;
    const int tx = threadIdx.x;
    const int nrows = min(32, N_NODES - row0);

    for (int r = 0; r < 32; ++r) {
        hs[r][tx] = (r < nrows) ? h[(size_t)(row0 + r) * DIM + tx] : 0.0f;
    }
    __syncthreads();

    float accq[32], acck[32];
#pragma unroll
    for (int r = 0; r < 32; ++r) { accq[r] = 0.0f; acck[r] = 0.0f; }

    for (int d4 = 0; d4 < DIM; d4 += 4) {
        float wq0 = Wq[(d4 + 0) * DIM + tx];
        float wq1 = Wq[(d4 + 1) * DIM + tx];
        float wq2 = Wq[(d4 + 2) * DIM + tx];
        float wq3 = Wq[(d4 + 3) * DIM + tx];
        float wk0 = Wk[(d4 + 0) * DIM + tx];
        float wk1 = Wk[(d4 + 1) * DIM + tx];
        float wk2 = Wk[(d4 + 2) * DIM + tx];
        float wk3 = Wk[(d4 + 3) * DIM + tx];
#pragma unroll
        for (int r = 0; r < 32; ++r) {
            float4 c4 = *reinterpret_cast<const float4*>(&hs[r][d4]);
            accq[r] = fmaf(c4.x, wq0, accq[r]);
            accq[r] = fmaf(c4.y, wq1, accq[r]);
            accq[r] = fmaf(c4.z, wq2, accq[r]);
            accq[r] = fmaf(c4.w, wq3, accq[r]);
            acck[r] = fmaf(c4.x, wk0, acck[r]);
            acck[r] = fmaf(c4.y, wk1, acck[r]);
            acck[r] = fmaf(c4.z, wk2, acck[r]);
            acck[r] = fmaf(c4.w, wk3, acck[r]);
        }
    }

    const float bqv = bq[tx];
    const float bkv = bk[tx];
    for (int r = 0; r < nrows; ++r) {
        size_t off = (size_t)(row0 + r) * DIM + tx;
        Q[off]    = accq[r] + bqv;
        Kall[off] = acck[r] + bkv;
    }
}

// ---------------------------------------------------------------------------
// Kernel 2: per-node attention. One block (256 threads) per node.
//  - mask layout auto-detected (int32 0/1 vs 1-byte bool): an int32 0/1
//    array never has bits >=8 set in any word; a byte-bool array at 80%
//    density almost surely does within the first 64 words.
//  - compact valid neighbor indices to front (stable)
//  - slot j: kv[j] = Kall[idx_c[j]] if j<count else bk
//  - scores masked at ORIGINAL positions, sigmoid -> softmax over 16 slots
//  - ctx = sum_j attn[head][j]*kv[j] + h[n]   (written to Ctx, may alias Q)
// ---------------------------------------------------------------------------
__global__ __launch_bounds__(256) void attn_kernel(
    const float* __restrict__ h,
    const int* __restrict__ nbr_idx,
    const void* __restrict__ nbr_mask_raw,
    const float* __restrict__ Q,
    const float* __restrict__ Kall,
    const float* __restrict__ bk,
    float* __restrict__ Ctx)
{
    const int n = blockIdx.x;
    const int t = threadIdx.x;

    __shared__ int s_idxc[K_NBR];
    __shared__ unsigned char s_mask[K_NBR];
    __shared__ float s_scores[H_HEADS][K_NBR];
    __shared__ float s_attn[H_HEADS][K_NBR];

    if (t == 0) {
        // ---- mask dtype detection (reads first 256 bytes, L2-broadcast) ----
        const unsigned int* mw = (const unsigned int*)nbr_mask_raw;
        unsigned int accbits = 0;
#pragma unroll
        for (int w = 0; w < 64; ++w) accbits |= mw[w];
        const bool is_byte_mask = (accbits & 0xFFFFFF00u) != 0;

        int c = 0;
#pragma unroll
        for (int j = 0; j < K_NBR; ++j) {
            unsigned char m;
            if (is_byte_mask) {
                m = ((const unsigned char*)nbr_mask_raw)[n * K_NBR + j] ? 1 : 0;
            } else {
                m = ((const int*)nbr_mask_raw)[n * K_NBR + j] ? 1 : 0;
            }
            s_mask[j] = m;
            if (m) s_idxc[c++] = nbr_idx[n * K_NBR + j];
        }
        for (int j = c; j < K_NBR; ++j) s_idxc[j] = -1;
    }
    __syncthreads();

    const float qv  = Q[(size_t)n * DIM + t];
    const float hv  = h[(size_t)n * DIM + t];
    const float bkv = bk[t];
    const int head  = t >> 5;

    float kv[K_NBR];
#pragma unroll
    for (int j = 0; j < K_NBR; ++j) {
        int idx = s_idxc[j];
        kv[j] = (idx >= 0) ? Kall[(size_t)idx * DIM + t] : bkv;
    }

    // per-head dot products: reduce q*k over the 32 lanes of each head group
#pragma unroll
    for (int j = 0; j < K_NBR; ++j) {
        float p = qv * kv[j];
        p += __shfl_xor(p, 16, 32);
        p += __shfl_xor(p, 8, 32);
        p += __shfl_xor(p, 4, 32);
        p += __shfl_xor(p, 2, 32);
        p += __shfl_xor(p, 1, 32);
        if ((t & 31) == 0) s_scores[head][j] = p;
    }
    __syncthreads();

    // sigmoid (with original-position mask) then softmax over 16 slots/head
    if (t < H_HEADS * K_NBR) {
        const int hh = t >> 4;
        const int j  = t & 15;
        float sc = s_scores[hh][j] * INV_SCALE;
        float v  = s_mask[j] ? sigmoidf_(sc) : 0.0f;  // sigmoid(-inf)=0
        float m = v;
        m = fmaxf(m, __shfl_xor(m, 8, 16));
        m = fmaxf(m, __shfl_xor(m, 4, 16));
        m = fmaxf(m, __shfl_xor(m, 2, 16));
        m = fmaxf(m, __shfl_xor(m, 1, 16));
        float e = __expf(v - m);
        float s = e;
        s += __shfl_xor(s, 8, 16);
        s += __shfl_xor(s, 4, 16);
        s += __shfl_xor(s, 2, 16);
        s += __shfl_xor(s, 1, 16);
        s_attn[hh][j] = e / s;
    }
    __syncthreads();

    float ctx = hv;  // residual
#pragma unroll
    for (int j = 0; j < K_NBR; ++j) {
        ctx = fmaf(s_attn[head][j], kv[j], ctx);
    }
    Ctx[(size_t)n * DIM + t] = ctx;
}

// ---------------------------------------------------------------------------
// Kernel 3: out = LN(ctx @ Wo + bo) * gamma + beta
// 32 rows per block, 256 threads; LN via wave reductions (8 rows per wave).
// ---------------------------------------------------------------------------
__global__ __launch_bounds__(256) void out_ln_kernel(
    const float* __restrict__ Ctx,
    const float* __restrict__ Wo, const float* __restrict__ bo,
    const float* __restrict__ gamma, const float* __restrict__ beta,
    float* __restrict__ out)
{
    __shared__ float cs[32][DIM];
    __shared__ float sg[O_DIM];
    __shared__ float sb[O_DIM];
    const int row0 = blockIdx.x * 32;
    const int tx = threadIdx.x;
    const int nrows = min(32, N_NODES - row0);

    sg[tx] = gamma[tx];
    sb[tx] = beta[tx];
    for (int r = 0; r < 32; ++r) {
        cs[r][tx] = (r < nrows) ? Ctx[(size_t)(row0 + r) * DIM + tx] : 0.0f;
    }
    __syncthreads();

    float acc[32];
#pragma unroll
    for (int r = 0; r < 32; ++r) acc[r] = 0.0f;

    for (int d4 = 0; d4 < DIM; d4 += 4) {
        float w0 = Wo[(d4 + 0) * O_DIM + tx];
        float w1 = Wo[(d4 + 1) * O_DIM + tx];
        float w2 = Wo[(d4 + 2) * O_DIM + tx];
        float w3 = Wo[(d4 + 3) * O_DIM + tx];
#pragma unroll
        for (int r = 0; r < 32; ++r) {
            float4 c4 = *reinterpret_cast<const float4*>(&cs[r][d4]);
            acc[r] = fmaf(c4.x, w0, acc[r]);
            acc[r] = fmaf(c4.y, w1, acc[r]);
            acc[r] = fmaf(c4.z, w2, acc[r]);
            acc[r] = fmaf(c4.w, w3, acc[r]);
        }
    }

    const float bov = bo[tx];
    __syncthreads();
#pragma unroll
    for (int r = 0; r < 32; ++r) cs[r][tx] = acc[r] + bov;
    __syncthreads();

    // LayerNorm: each wave handles 8 rows; lane covers 4 columns
    const int wid = tx >> 6;
    const int lane = tx & 63;
    for (int r8 = 0; r8 < 8; ++r8) {
        const int r = wid * 8 + r8;
        float v0 = cs[r][lane];
        float v1 = cs[r][lane + 64];
        float v2 = cs[r][lane + 128];
        float v3 = cs[r][lane + 192];
        float s  = v0 + v1 + v2 + v3;
        float sq = v0 * v0 + v1 * v1 + v2 * v2 + v3 * v3;
#pragma unroll
        for (int off = 32; off; off >>= 1) {
            s  += __shfl_xor(s, off, 64);
            sq += __shfl_xor(sq, off, 64);
        }
        const float mu  = s * (1.0f / 256.0f);
        const float var = sq * (1.0f / 256.0f) - mu * mu;
        const float inv = rsqrtf(var + EPS);
        if (r < nrows) {
            size_t base = (size_t)(row0 + r) * O_DIM;
            out[base + lane]       = (v0 - mu) * inv * sg[lane]       + sb[lane];
            out[base + lane + 64]  = (v1 - mu) * inv * sg[lane + 64]  + sb[lane + 64];
            out[base + lane + 128] = (v2 - mu) * inv * sg[lane + 128] + sb[lane + 128];
            out[base + lane + 192] = (v3 - mu) * inv * sg[lane + 192] + sb[lane + 192];
        }
    }
}

// ---------------------------------------------------------------------------
extern "C" void kernel_launch(void* const* d_in, const int* in_sizes, int n_in,
                              void* d_out, int out_size, void* d_ws, size_t ws_size,
                              hipStream_t stream) {
    const float* h          = (const float*)d_in[0];
    const int* nbr_idx      = (const int*)d_in[1];
    const void* nbr_mask    = (const void*)d_in[2];   // dtype auto-detected in-kernel
    const float* Wq_w       = (const float*)d_in[3];
    const float* Wq_b       = (const float*)d_in[4];
    const float* Wk_w       = (const float*)d_in[5];
    const float* Wk_b       = (const float*)d_in[6];
    const float* Wo_w       = (const float*)d_in[7];
    const float* Wo_b       = (const float*)d_in[8];
    const float* gamma      = (const float*)d_in[9];
    const float* beta       = (const float*)d_in[10];
    float* out = (float*)d_out;

    float* Q    = (float*)d_ws;                       // N*256 floats
    float* Kall = Q + (size_t)N_NODES * DIM;          // N*256 floats
    float* Ctx  = Q;  // alias: each block reads Q[n] before writing Ctx[n]

    const int row_blocks = (N_NODES + 31) / 32;
    hipLaunchKernelGGL(qk_proj_kernel, dim3(row_blocks), dim3(256), 0, stream,
                       h, Wq_w, Wq_b, Wk_w, Wk_b, Q, Kall);
    hipLaunchKernelGGL(attn_kernel, dim3(N_NODES), dim3(256), 0, stream,
                       h, nbr_idx, nbr_mask, Q, Kall, Wk_b, Ctx);
    hipLaunchKernelGGL(out_ln_kernel, dim3(row_blocks), dim3(256), 0, stream,
                       Ctx, Wo_w, Wo_b, gamma, beta, out);
}

// Round 3
// 432.999 us; speedup vs baseline: 1.4197x; 1.4197x over previous
//
#include <hip/hip_runtime.h>
#include <hip/hip_bf16.h>
#include <math.h>

#define M_NODES 50000
#define K_NBR   16
#define DIM     256
#define H_HEADS 8
#define EPS     1e-5f
#define INV_SCALE 0.17677669529663687f  // 1/sqrt(32)

typedef __attribute__((ext_vector_type(8))) short short8;
typedef __attribute__((ext_vector_type(4))) float f32x4;
typedef __attribute__((ext_vector_type(4))) unsigned short ushort4v;

__device__ __forceinline__ unsigned short f2bf(float f) {
    unsigned x = __float_as_uint(f);
    x += 0x7FFFu + ((x >> 16) & 1u);          // round-to-nearest-even
    return (unsigned short)(x >> 16);
}
__device__ __forceinline__ float bf2f(unsigned short u) {
    return __uint_as_float(((unsigned)u) << 16);
}
__device__ __forceinline__ float sigmoidf_(float x) {
    return 1.0f / (1.0f + __expf(-x));
}

// ---------------------------------------------------------------------------
// Kernel 0: convert h -> bf16; build transposed bf16 weights:
//   WqkT[n][k] = (n<256 ? Wq[k][n] : Wk[k][n-256]),  WoT[n][k] = Wo[k][n]
// ---------------------------------------------------------------------------
__global__ __launch_bounds__(256) void prep_kernel(
    const float* __restrict__ h, const float* __restrict__ Wq,
    const float* __restrict__ Wk, const float* __restrict__ Wo,
    unsigned short* __restrict__ hb, unsigned short* __restrict__ WqkT,
    unsigned short* __restrict__ WoT)
{
    const int NH4 = M_NODES * DIM / 4;  // 3,200,000 float4 groups
    int i = blockIdx.x * 256 + threadIdx.x;
    if (i < NH4) {
        float4 v = reinterpret_cast<const float4*>(h)[i];
        ushort4v o;
        o.x = f2bf(v.x); o.y = f2bf(v.y); o.z = f2bf(v.z); o.w = f2bf(v.w);
        reinterpret_cast<ushort4v*>(hb)[i] = o;
    } else if (i < NH4 + 512 * 256) {
        int j = i - NH4; int n = j >> 8, k = j & 255;
        float v = (n < 256) ? Wq[k * 256 + n] : Wk[k * 256 + (n - 256)];
        WqkT[j] = f2bf(v);
    } else if (i < NH4 + 512 * 256 + 256 * 256) {
        int j = i - NH4 - 512 * 256; int n = j >> 8, k = j & 255;
        WoT[j] = f2bf(Wo[k * 256 + n]);
    }
}

// ---------------------------------------------------------------------------
// MFMA GEMM: C[M x NTOT] = A[M x 256] @ Bt[NTOT x 256]^T (+bias)
// 128x128 tile, 4 waves (2x2), each wave 64x64 = 4x4 frags of 16x16x32 bf16.
// K staged in 2 chunks of 128; LDS tiles XOR-swizzled (row&7)<<4 to kill the
// 16-way bank conflict of 256B-stride fragment reads.
// OUTMODE 0: bf16 out split at col 256 into o_bf0 / o_bf1 (Q / K).
// OUTMODE 1: fp32 out to o_f32.
// ---------------------------------------------------------------------------
template<int NTOT, int OUTMODE>
__global__ __launch_bounds__(256) void gemm_kernel(
    const unsigned short* __restrict__ A,
    const unsigned short* __restrict__ Bt,
    const float* __restrict__ bias0, const float* __restrict__ bias1,
    unsigned short* __restrict__ o_bf0, unsigned short* __restrict__ o_bf1,
    float* __restrict__ o_f32)
{
    __shared__ __align__(16) char sA[128 * 256];
    __shared__ __align__(16) char sB[128 * 256];
    const int m0 = blockIdx.x * 128;
    const int n0 = blockIdx.y * 128;
    const int t = threadIdx.x;
    const int lane = t & 63;
    const int w = t >> 6;
    const int wr = w >> 1, wc = w & 1;

    f32x4 acc[4][4];
#pragma unroll
    for (int a = 0; a < 4; ++a)
#pragma unroll
        for (int b = 0; b < 4; ++b) acc[a][b] = (f32x4){0.f, 0.f, 0.f, 0.f};

    const char* Ab = (const char*)A;
    const char* Bb = (const char*)Bt;

    for (int kt = 0; kt < 512; kt += 256) {  // byte offset within 512B rows
        // ---- stage 32KB A-tile + 32KB B-tile (reg->LDS, swizzled) ----
#pragma unroll
        for (int i = 0; i < 8; ++i) {
            int o = i * 4096 + t * 16;          // linear byte offset in tile
            int srow = o >> 8;                   // 256B per row
            int scol = o & 255;
            int lo = o ^ ((srow & 7) << 4);      // swizzled LDS slot
            int ga = m0 + srow; ga = (ga < M_NODES) ? ga : (M_NODES - 1);
            short8 va = *reinterpret_cast<const short8*>(Ab + (size_t)ga * 512 + kt + scol);
            *reinterpret_cast<short8*>(sA + lo) = va;
            int gb = n0 + srow;                  // always < NTOT
            short8 vb = *reinterpret_cast<const short8*>(Bb + (size_t)gb * 512 + kt + scol);
            *reinterpret_cast<short8*>(sB + lo) = vb;
        }
        __syncthreads();
        // ---- 4 K-steps of 32 ----
#pragma unroll
        for (int ks = 0; ks < 4; ++ks) {
            const int kb = ks * 64 + (lane >> 4) * 16;  // byte offset in row
            short8 af[4], bfr[4];
#pragma unroll
            for (int mi = 0; mi < 4; ++mi) {
                int row = wr * 64 + mi * 16 + (lane & 15);
                af[mi] = *reinterpret_cast<const short8*>(
                    sA + ((row << 8) | (kb ^ ((row & 7) << 4))));
            }
#pragma unroll
            for (int ni = 0; ni < 4; ++ni) {
                int row = wc * 64 + ni * 16 + (lane & 15);
                bfr[ni] = *reinterpret_cast<const short8*>(
                    sB + ((row << 8) | (kb ^ ((row & 7) << 4))));
            }
#pragma unroll
            for (int mi = 0; mi < 4; ++mi)
#pragma unroll
                for (int ni = 0; ni < 4; ++ni)
                    acc[mi][ni] = __builtin_amdgcn_mfma_f32_16x16x32_bf16(
                        af[mi], bfr[ni], acc[mi][ni], 0, 0, 0);
        }
        __syncthreads();
    }

    // ---- epilogue: bias, convert, store ----
#pragma unroll
    for (int ni = 0; ni < 4; ++ni) {
        int gcol = n0 + wc * 64 + ni * 16 + (lane & 15);
        float bias;
        if (OUTMODE == 0) bias = (gcol < 256) ? bias0[gcol] : bias1[gcol - 256];
        else              bias = bias0[gcol];
#pragma unroll
        for (int mi = 0; mi < 4; ++mi) {
#pragma unroll
            for (int q = 0; q < 4; ++q) {
                int grow = m0 + wr * 64 + mi * 16 + (lane >> 4) * 4 + q;
                if (grow < M_NODES) {
                    float v = acc[mi][ni][q] + bias;
                    if (OUTMODE == 0) {
                        if (gcol < 256) o_bf0[(size_t)grow * 256 + gcol] = f2bf(v);
                        else            o_bf1[(size_t)grow * 256 + (gcol - 256)] = f2bf(v);
                    } else {
                        o_f32[(size_t)grow * 256 + gcol] = v;
                    }
                }
            }
        }
    }
}

// ---------------------------------------------------------------------------
// Attention: one block (256 threads) per node. Same verified structure as
// round 2, with bf16 Q/K reads and bf16 Ctx write (Ctx aliases Q).
// ---------------------------------------------------------------------------
__global__ __launch_bounds__(256) void attn_kernel(
    const float* __restrict__ h,
    const int* __restrict__ nbr_idx,
    const void* __restrict__ nbr_mask_raw,
    const unsigned short* __restrict__ Qb,
    const unsigned short* __restrict__ Kb,
    const float* __restrict__ bk,
    unsigned short* __restrict__ Ctxb)
{
    const int n = blockIdx.x;
    const int t = threadIdx.x;

    __shared__ int s_idxc[K_NBR];
    __shared__ unsigned char s_mask[K_NBR];
    __shared__ float s_scores[H_HEADS][K_NBR];
    __shared__ float s_attn[H_HEADS][K_NBR];

    if (t == 0) {
        const unsigned int* mw = (const unsigned int*)nbr_mask_raw;
        unsigned int accbits = 0;
#pragma unroll
        for (int w = 0; w < 64; ++w) accbits |= mw[w];
        const bool is_byte_mask = (accbits & 0xFFFFFF00u) != 0;

        int c = 0;
#pragma unroll
        for (int j = 0; j < K_NBR; ++j) {
            unsigned char m;
            if (is_byte_mask) m = ((const unsigned char*)nbr_mask_raw)[n * K_NBR + j] ? 1 : 0;
            else              m = ((const int*)nbr_mask_raw)[n * K_NBR + j] ? 1 : 0;
            s_mask[j] = m;
            if (m) s_idxc[c++] = nbr_idx[n * K_NBR + j];
        }
        for (int j = c; j < K_NBR; ++j) s_idxc[j] = -1;
    }
    __syncthreads();

    const float qv  = bf2f(Qb[(size_t)n * DIM + t]);
    const float hv  = h[(size_t)n * DIM + t];
    const float bkv = bk[t];
    const int head  = t >> 5;

    float kv[K_NBR];
#pragma unroll
    for (int j = 0; j < K_NBR; ++j) {
        int idx = s_idxc[j];
        kv[j] = (idx >= 0) ? bf2f(Kb[(size_t)idx * DIM + t]) : bkv;
    }

#pragma unroll
    for (int j = 0; j < K_NBR; ++j) {
        float p = qv * kv[j];
        p += __shfl_xor(p, 16, 32);
        p += __shfl_xor(p, 8, 32);
        p += __shfl_xor(p, 4, 32);
        p += __shfl_xor(p, 2, 32);
        p += __shfl_xor(p, 1, 32);
        if ((t & 31) == 0) s_scores[head][j] = p;
    }
    __syncthreads();

    if (t < H_HEADS * K_NBR) {
        const int hh = t >> 4;
        const int j  = t & 15;
        float sc = s_scores[hh][j] * INV_SCALE;
        float v  = s_mask[j] ? sigmoidf_(sc) : 0.0f;  // sigmoid(-inf)=0
        float m = v;
        m = fmaxf(m, __shfl_xor(m, 8, 16));
        m = fmaxf(m, __shfl_xor(m, 4, 16));
        m = fmaxf(m, __shfl_xor(m, 2, 16));
        m = fmaxf(m, __shfl_xor(m, 1, 16));
        float e = __expf(v - m);
        float s = e;
        s += __shfl_xor(s, 8, 16);
        s += __shfl_xor(s, 4, 16);
        s += __shfl_xor(s, 2, 16);
        s += __shfl_xor(s, 1, 16);
        s_attn[hh][j] = e / s;
    }
    __syncthreads();

    float ctx = hv;  // residual
#pragma unroll
    for (int j = 0; j < K_NBR; ++j) {
        ctx = fmaf(s_attn[head][j], kv[j], ctx);
    }
    Ctxb[(size_t)n * DIM + t] = f2bf(ctx);
}

// ---------------------------------------------------------------------------
// LayerNorm over pre-LN fp32 rows -> final output.
// ---------------------------------------------------------------------------
__global__ __launch_bounds__(256) void ln_kernel(
    const float* __restrict__ pre, const float* __restrict__ gamma,
    const float* __restrict__ beta, float* __restrict__ out)
{
    const int wid = threadIdx.x >> 6, lane = threadIdx.x & 63;
    float4 g4 = reinterpret_cast<const float4*>(gamma)[lane];
    float4 b4 = reinterpret_cast<const float4*>(beta)[lane];
    for (int r = 0; r < 8; ++r) {
        int row = blockIdx.x * 32 + wid * 8 + r;
        if (row >= M_NODES) break;
        float4 v = reinterpret_cast<const float4*>(pre + (size_t)row * 256)[lane];
        float s  = v.x + v.y + v.z + v.w;
        float sq = v.x * v.x + v.y * v.y + v.z * v.z + v.w * v.w;
#pragma unroll
        for (int off = 32; off; off >>= 1) {
            s  += __shfl_xor(s, off, 64);
            sq += __shfl_xor(sq, off, 64);
        }
        float mu  = s * (1.f / 256.f);
        float var = sq * (1.f / 256.f) - mu * mu;
        float inv = rsqrtf(var + EPS);
        float4 o;
        o.x = (v.x - mu) * inv * g4.x + b4.x;
        o.y = (v.y - mu) * inv * g4.y + b4.y;
        o.z = (v.z - mu) * inv * g4.z + b4.z;
        o.w = (v.w - mu) * inv * g4.w + b4.w;
        reinterpret_cast<float4*>(out + (size_t)row * 256)[lane] = o;
    }
}

// ---------------------------------------------------------------------------
extern "C" void kernel_launch(void* const* d_in, const int* in_sizes, int n_in,
                              void* d_out, int out_size, void* d_ws, size_t ws_size,
                              hipStream_t stream) {
    const float* h       = (const float*)d_in[0];
    const int* nbr_idx   = (const int*)d_in[1];
    const void* nbr_mask = (const void*)d_in[2];
    const float* Wq_w    = (const float*)d_in[3];
    const float* Wq_b    = (const float*)d_in[4];
    const float* Wk_w    = (const float*)d_in[5];
    const float* Wk_b    = (const float*)d_in[6];
    const float* Wo_w    = (const float*)d_in[7];
    const float* Wo_b    = (const float*)d_in[8];
    const float* gamma   = (const float*)d_in[9];
    const float* beta    = (const float*)d_in[10];
    float* out = (float*)d_out;

    // ws layout (bytes): [Qb/Ctxb 25.6M][Kb 25.6M][hb 25.6M][WqkT 256K][WoT 128K]
    // out_pre (fp32, 51.2M) aliases [Kb][hb] (both dead by gemm_out).
    char* ws = (char*)d_ws;
    unsigned short* Qb   = (unsigned short*)(ws);
    unsigned short* Kb   = (unsigned short*)(ws + 25600000);
    unsigned short* hb   = (unsigned short*)(ws + 51200000);
    unsigned short* WqkT = (unsigned short*)(ws + 76800000);
    unsigned short* WoT  = (unsigned short*)(ws + 77062144);
    float* out_pre       = (float*)(ws + 25600000);

    hipLaunchKernelGGL(prep_kernel, dim3(13268), dim3(256), 0, stream,
                       h, Wq_w, Wk_w, Wo_w, hb, WqkT, WoT);
    hipLaunchKernelGGL((gemm_kernel<512, 0>), dim3(391, 4), dim3(256), 0, stream,
                       hb, WqkT, Wq_b, Wk_b, Qb, Kb, (float*)nullptr);
    hipLaunchKernelGGL(attn_kernel, dim3(M_NODES), dim3(256), 0, stream,
                       h, nbr_idx, nbr_mask, Qb, Kb, Wk_b, Qb /*Ctx aliases Q*/);
    hipLaunchKernelGGL((gemm_kernel<256, 1>), dim3(391, 2), dim3(256), 0, stream,
                       Qb /*Ctx*/, WoT, Wo_b, (const float*)nullptr,
                       (unsigned short*)nullptr, (unsigned short*)nullptr, out_pre);
    hipLaunchKernelGGL(ln_kernel, dim3(1563), dim3(256), 0, stream,
                       out_pre, gamma, beta, out);
}

// Round 4
// 200.152 us; speedup vs baseline: 3.0712x; 2.1634x over previous
//
#include <hip/hip_runtime.h>
#include <hip/hip_bf16.h>
#include <math.h>

#define M_NODES 50000
#define K_NBR   16
#define DIM     256
#define H_HEADS 8
#define EPS     1e-5f
#define INV_SCALE 0.17677669529663687f  // 1/sqrt(32)

typedef __attribute__((ext_vector_type(8))) short short8;
typedef __attribute__((ext_vector_type(4))) float f32x4;
typedef __attribute__((ext_vector_type(4))) unsigned short ushort4v;

__device__ __forceinline__ unsigned short f2bf(float f) {
    unsigned x = __float_as_uint(f);
    x += 0x7FFFu + ((x >> 16) & 1u);          // round-to-nearest-even
    return (unsigned short)(x >> 16);
}
__device__ __forceinline__ float bf2f(unsigned short u) {
    return __uint_as_float(((unsigned)u) << 16);
}
__device__ __forceinline__ float bflo(unsigned int u) {   // low bf16 of dword
    return __uint_as_float(u << 16);
}
__device__ __forceinline__ float bfhi(unsigned int u) {   // high bf16 of dword
    return __uint_as_float(u & 0xFFFF0000u);
}
__device__ __forceinline__ float sigmoidf_(float x) {
    return 1.0f / (1.0f + __expf(-x));
}

// ---------------------------------------------------------------------------
// Kernel 0: convert h -> bf16; build transposed bf16 weights:
//   WqkT[n][k] = (n<256 ? Wq[k][n] : Wk[k][n-256]),  WoT[n][k] = Wo[k][n]
// ---------------------------------------------------------------------------
__global__ __launch_bounds__(256) void prep_kernel(
    const float* __restrict__ h, const float* __restrict__ Wq,
    const float* __restrict__ Wk, const float* __restrict__ Wo,
    unsigned short* __restrict__ hb, unsigned short* __restrict__ WqkT,
    unsigned short* __restrict__ WoT)
{
    const int NH4 = M_NODES * DIM / 4;  // 3,200,000 float4 groups
    int i = blockIdx.x * 256 + threadIdx.x;
    if (i < NH4) {
        float4 v = reinterpret_cast<const float4*>(h)[i];
        ushort4v o;
        o.x = f2bf(v.x); o.y = f2bf(v.y); o.z = f2bf(v.z); o.w = f2bf(v.w);
        reinterpret_cast<ushort4v*>(hb)[i] = o;
    } else if (i < NH4 + 512 * 256) {
        int j = i - NH4; int n = j >> 8, k = j & 255;
        float v = (n < 256) ? Wq[k * 256 + n] : Wk[k * 256 + (n - 256)];
        WqkT[j] = f2bf(v);
    } else if (i < NH4 + 512 * 256 + 256 * 256) {
        int j = i - NH4 - 512 * 256; int n = j >> 8, k = j & 255;
        WoT[j] = f2bf(Wo[k * 256 + n]);
    }
}

// ---------------------------------------------------------------------------
// MFMA GEMM: C[M x NTOT] = A[M x 256] @ Bt[NTOT x 256]^T (+bias)
// 128x128 tile, 4 waves (2x2), each wave 64x64 = 4x4 frags of 16x16x32 bf16.
// LDS tiles XOR-swizzled (row&7)<<4 against 256B-stride bank conflicts.
// OUTMODE 0: bf16 out split at col 256 into o_bf0 / o_bf1 (Q / K).
// OUTMODE 1: fp32 out to o_f32.
// ---------------------------------------------------------------------------
template<int NTOT, int OUTMODE>
__global__ __launch_bounds__(256) void gemm_kernel(
    const unsigned short* __restrict__ A,
    const unsigned short* __restrict__ Bt,
    const float* __restrict__ bias0, const float* __restrict__ bias1,
    unsigned short* __restrict__ o_bf0, unsigned short* __restrict__ o_bf1,
    float* __restrict__ o_f32)
{
    __shared__ __align__(16) char sA[128 * 256];
    __shared__ __align__(16) char sB[128 * 256];
    const int m0 = blockIdx.x * 128;
    const int n0 = blockIdx.y * 128;
    const int t = threadIdx.x;
    const int lane = t & 63;
    const int w = t >> 6;
    const int wr = w >> 1, wc = w & 1;

    f32x4 acc[4][4];
#pragma unroll
    for (int a = 0; a < 4; ++a)
#pragma unroll
        for (int b = 0; b < 4; ++b) acc[a][b] = (f32x4){0.f, 0.f, 0.f, 0.f};

    const char* Ab = (const char*)A;
    const char* Bb = (const char*)Bt;

    for (int kt = 0; kt < 512; kt += 256) {  // byte offset within 512B rows
#pragma unroll
        for (int i = 0; i < 8; ++i) {
            int o = i * 4096 + t * 16;
            int srow = o >> 8;
            int scol = o & 255;
            int lo = o ^ ((srow & 7) << 4);
            int ga = m0 + srow; ga = (ga < M_NODES) ? ga : (M_NODES - 1);
            short8 va = *reinterpret_cast<const short8*>(Ab + (size_t)ga * 512 + kt + scol);
            *reinterpret_cast<short8*>(sA + lo) = va;
            int gb = n0 + srow;
            short8 vb = *reinterpret_cast<const short8*>(Bb + (size_t)gb * 512 + kt + scol);
            *reinterpret_cast<short8*>(sB + lo) = vb;
        }
        __syncthreads();
#pragma unroll
        for (int ks = 0; ks < 4; ++ks) {
            const int kb = ks * 64 + (lane >> 4) * 16;
            short8 af[4], bfr[4];
#pragma unroll
            for (int mi = 0; mi < 4; ++mi) {
                int row = wr * 64 + mi * 16 + (lane & 15);
                af[mi] = *reinterpret_cast<const short8*>(
                    sA + ((row << 8) | (kb ^ ((row & 7) << 4))));
            }
#pragma unroll
            for (int ni = 0; ni < 4; ++ni) {
                int row = wc * 64 + ni * 16 + (lane & 15);
                bfr[ni] = *reinterpret_cast<const short8*>(
                    sB + ((row << 8) | (kb ^ ((row & 7) << 4))));
            }
#pragma unroll
            for (int mi = 0; mi < 4; ++mi)
#pragma unroll
                for (int ni = 0; ni < 4; ++ni)
                    acc[mi][ni] = __builtin_amdgcn_mfma_f32_16x16x32_bf16(
                        af[mi], bfr[ni], acc[mi][ni], 0, 0, 0);
        }
        __syncthreads();
    }

#pragma unroll
    for (int ni = 0; ni < 4; ++ni) {
        int gcol = n0 + wc * 64 + ni * 16 + (lane & 15);
        float bias;
        if (OUTMODE == 0) bias = (gcol < 256) ? bias0[gcol] : bias1[gcol - 256];
        else              bias = bias0[gcol];
#pragma unroll
        for (int mi = 0; mi < 4; ++mi) {
#pragma unroll
            for (int q = 0; q < 4; ++q) {
                int grow = m0 + wr * 64 + mi * 16 + (lane >> 4) * 4 + q;
                if (grow < M_NODES) {
                    float v = acc[mi][ni][q] + bias;
                    if (OUTMODE == 0) {
                        if (gcol < 256) o_bf0[(size_t)grow * 256 + gcol] = f2bf(v);
                        else            o_bf1[(size_t)grow * 256 + (gcol - 256)] = f2bf(v);
                    } else {
                        o_f32[(size_t)grow * 256 + gcol] = v;
                    }
                }
            }
        }
    }
}

// ---------------------------------------------------------------------------
// Attention: ONE WAVE per node, no LDS, no barriers. Lane l owns cols
// 4l..4l+3 (head = l>>3). Compaction via ballot + static ctz chain (all
// register arrays statically indexed). Per-slot head-dot via 3-step
// width-8 butterfly; softmax fully lane-local (each lane holds all 16
// scores of its head). kv kept as packed bf16 (uint2, 2 VGPR/slot).
// ---------------------------------------------------------------------------
__global__ __launch_bounds__(256) void attn_kernel(
    const float* __restrict__ h,
    const int* __restrict__ nbr_idx,
    const void* __restrict__ nbr_mask_raw,
    const unsigned short* __restrict__ Qb,
    const unsigned short* __restrict__ Kb,
    const float* __restrict__ bk,
    unsigned short* __restrict__ Ctxb)
{
    const int wid  = threadIdx.x >> 6;
    const int lane = threadIdx.x & 63;
    const int n    = blockIdx.x * 4 + wid;

    // ---- mask dtype detect: lane l inspects word l of first 256 bytes ----
    const unsigned int* mw = (const unsigned int*)nbr_mask_raw;
    unsigned long long det = __ballot((mw[lane] & 0xFFFFFF00u) != 0u);
    const bool is_byte = (det != 0ull);

    // ---- per-node mask bits + neighbor idx (lanes 0..15) ----
    unsigned int mbit = 0;
    int idxv = 0;
    if (lane < K_NBR) {
        if (is_byte) mbit = ((const unsigned char*)nbr_mask_raw)[n * K_NBR + lane] ? 1u : 0u;
        else         mbit = ((const int*)nbr_mask_raw)[n * K_NBR + lane] ? 1u : 0u;
        idxv = nbr_idx[n * K_NBR + lane];
    }
    unsigned long long bal = __ballot(mbit != 0u);
    const unsigned int mask16 = (unsigned int)(bal & 0xFFFFull);

    // ---- compacted row list: slot s = index of s-th set bit (stable) ----
    int rows[K_NBR];
    unsigned int mm = mask16;
#pragma unroll
    for (int s = 0; s < K_NBR; ++s) {
        int j = __ffs(mm) - 1;                 // -1 when exhausted (uniform)
        int r = __shfl(idxv, (j < 0) ? 0 : j, 64);
        rows[s] = (j >= 0) ? r : -1;
        mm &= mm - 1;
    }

    // ---- loads (all issued before use) ----
    const float4 h4 = *reinterpret_cast<const float4*>(h + (size_t)n * DIM + 4 * lane);
    const uint2  qp = *reinterpret_cast<const uint2*>(Qb + (size_t)n * DIM + 4 * lane);
    const float4 b4 = *reinterpret_cast<const float4*>(bk + 4 * lane);
    uint2 bkp;
    bkp.x = (unsigned)f2bf(b4.x) | ((unsigned)f2bf(b4.y) << 16);
    bkp.y = (unsigned)f2bf(b4.z) | ((unsigned)f2bf(b4.w) << 16);

    uint2 kvp[K_NBR];
#pragma unroll
    for (int s = 0; s < K_NBR; ++s) {
        kvp[s] = (rows[s] >= 0)
            ? *reinterpret_cast<const uint2*>(Kb + (size_t)rows[s] * DIM + 4 * lane)
            : bkp;
    }

    const float q0 = bflo(qp.x), q1 = bfhi(qp.x), q2 = bflo(qp.y), q3 = bfhi(qp.y);

    // ---- per-slot head dot: lane-local partial + width-8 butterfly ----
    float p[K_NBR];
#pragma unroll
    for (int s = 0; s < K_NBR; ++s) {
        float a = q0 * bflo(kvp[s].x) + q1 * bfhi(kvp[s].x)
                + q2 * bflo(kvp[s].y) + q3 * bfhi(kvp[s].y);
        a += __shfl_xor(a, 1, 8);
        a += __shfl_xor(a, 2, 8);
        a += __shfl_xor(a, 4, 8);
        p[s] = a;   // full 32-dim dot for head (lane>>3), all lanes of group
    }

    // ---- sigmoid (mask at ORIGINAL positions) -> softmax, lane-local ----
#pragma unroll
    for (int s = 0; s < K_NBR; ++s) {
        float v = ((mask16 >> s) & 1u) ? sigmoidf_(p[s] * INV_SCALE) : 0.0f;
        p[s] = v;
    }
    float mx = p[0];
#pragma unroll
    for (int s = 1; s < K_NBR; ++s) mx = fmaxf(mx, p[s]);
    float sum = 0.0f;
#pragma unroll
    for (int s = 0; s < K_NBR; ++s) { float e = __expf(p[s] - mx); p[s] = e; sum += e; }
    const float inv = 1.0f / sum;

    // ---- ctx = h + softmax @ kv ----
    float c0 = 0.f, c1 = 0.f, c2 = 0.f, c3 = 0.f;
#pragma unroll
    for (int s = 0; s < K_NBR; ++s) {
        c0 = fmaf(p[s], bflo(kvp[s].x), c0);
        c1 = fmaf(p[s], bfhi(kvp[s].x), c1);
        c2 = fmaf(p[s], bflo(kvp[s].y), c2);
        c3 = fmaf(p[s], bfhi(kvp[s].y), c3);
    }
    const float r0 = h4.x + c0 * inv;
    const float r1 = h4.y + c1 * inv;
    const float r2 = h4.z + c2 * inv;
    const float r3 = h4.w + c3 * inv;

    uint2 o;
    o.x = (unsigned)f2bf(r0) | ((unsigned)f2bf(r1) << 16);
    o.y = (unsigned)f2bf(r2) | ((unsigned)f2bf(r3) << 16);
    *reinterpret_cast<uint2*>(Ctxb + (size_t)n * DIM + 4 * lane) = o;
}

// ---------------------------------------------------------------------------
// LayerNorm over pre-LN fp32 rows -> final output.
// ---------------------------------------------------------------------------
__global__ __launch_bounds__(256) void ln_kernel(
    const float* __restrict__ pre, const float* __restrict__ gamma,
    const float* __restrict__ beta, float* __restrict__ out)
{
    const int wid = threadIdx.x >> 6, lane = threadIdx.x & 63;
    float4 g4 = reinterpret_cast<const float4*>(gamma)[lane];
    float4 b4 = reinterpret_cast<const float4*>(beta)[lane];
    for (int r = 0; r < 8; ++r) {
        int row = blockIdx.x * 32 + wid * 8 + r;
        if (row >= M_NODES) break;
        float4 v = reinterpret_cast<const float4*>(pre + (size_t)row * 256)[lane];
        float s  = v.x + v.y + v.z + v.w;
        float sq = v.x * v.x + v.y * v.y + v.z * v.z + v.w * v.w;
#pragma unroll
        for (int off = 32; off; off >>= 1) {
            s  += __shfl_xor(s, off, 64);
            sq += __shfl_xor(sq, off, 64);
        }
        float mu  = s * (1.f / 256.f);
        float var = sq * (1.f / 256.f) - mu * mu;
        float inv = rsqrtf(var + EPS);
        float4 o;
        o.x = (v.x - mu) * inv * g4.x + b4.x;
        o.y = (v.y - mu) * inv * g4.y + b4.y;
        o.z = (v.z - mu) * inv * g4.z + b4.z;
        o.w = (v.w - mu) * inv * g4.w + b4.w;
        reinterpret_cast<float4*>(out + (size_t)row * 256)[lane] = o;
    }
}

// ---------------------------------------------------------------------------
extern "C" void kernel_launch(void* const* d_in, const int* in_sizes, int n_in,
                              void* d_out, int out_size, void* d_ws, size_t ws_size,
                              hipStream_t stream) {
    const float* h       = (const float*)d_in[0];
    const int* nbr_idx   = (const int*)d_in[1];
    const void* nbr_mask = (const void*)d_in[2];
    const float* Wq_w    = (const float*)d_in[3];
    const float* Wq_b    = (const float*)d_in[4];
    const float* Wk_w    = (const float*)d_in[5];
    const float* Wk_b    = (const float*)d_in[6];
    const float* Wo_w    = (const float*)d_in[7];
    const float* Wo_b    = (const float*)d_in[8];
    const float* gamma   = (const float*)d_in[9];
    const float* beta    = (const float*)d_in[10];
    float* out = (float*)d_out;

    // ws layout (bytes): [Qb/Ctxb 25.6M][Kb 25.6M][hb 25.6M][WqkT 256K][WoT 128K]
    // out_pre (fp32, 51.2M) aliases [Kb][hb] (both dead by gemm_out).
    char* ws = (char*)d_ws;
    unsigned short* Qb   = (unsigned short*)(ws);
    unsigned short* Kb   = (unsigned short*)(ws + 25600000);
    unsigned short* hb   = (unsigned short*)(ws + 51200000);
    unsigned short* WqkT = (unsigned short*)(ws + 76800000);
    unsigned short* WoT  = (unsigned short*)(ws + 77062144);
    float* out_pre       = (float*)(ws + 25600000);

    hipLaunchKernelGGL(prep_kernel, dim3(13268), dim3(256), 0, stream,
                       h, Wq_w, Wk_w, Wo_w, hb, WqkT, WoT);
    hipLaunchKernelGGL((gemm_kernel<512, 0>), dim3(391, 4), dim3(256), 0, stream,
                       hb, WqkT, Wq_b, Wk_b, Qb, Kb, (float*)nullptr);
    hipLaunchKernelGGL(attn_kernel, dim3(12500), dim3(256), 0, stream,
                       h, nbr_idx, nbr_mask, Qb, Kb, Wk_b, Qb /*Ctx aliases Q*/);
    hipLaunchKernelGGL((gemm_kernel<256, 1>), dim3(391, 2), dim3(256), 0, stream,
                       Qb /*Ctx*/, WoT, Wo_b, (const float*)nullptr,
                       (unsigned short*)nullptr, (unsigned short*)nullptr, out_pre);
    hipLaunchKernelGGL(ln_kernel, dim3(1563), dim3(256), 0, stream,
                       out_pre, gamma, beta, out);
}